// Round 15
// baseline (1080.276 us; speedup 1.0000x reference)
//
#include <hip/hip_runtime.h>
#include <cstdint>

#define NN 524288       // total nodes = B*S
#define NB 65536        // batch
#define NQ 9
#define NEDGE 2097152
#define NITERS 3
#define NBUCK 256       // dst-buckets (2048 nodes each)
#define BCAP 16384      // slots per bucket (expected 8192, 2x headroom)

typedef __attribute__((ext_vector_type(8))) short bf16x8;
typedef __attribute__((ext_vector_type(4))) float f32x4;

// ---------------- bf16 helpers (bit-level, RNE) ----------------
__device__ __forceinline__ unsigned short f2b(float f) {
    union { float f; unsigned u; } v; v.f = f;
    unsigned u = v.u;
    u += 0x7FFFu + ((u >> 16) & 1u);
    return (unsigned short)(u >> 16);
}
__device__ __forceinline__ float b2f(unsigned short b) {
    union { unsigned u; float f; } v; v.u = ((unsigned)b) << 16;
    return v.f;
}
__device__ __forceinline__ float frelu(float v) { return v > 0.f ? v : 0.f; }

// Swizzled LDS index (ushort units): XOR row&7 into ushort-col bits 3..5.
__device__ __forceinline__ int sw64(int r, int c)  { return r * 64  + (c ^ ((r & 7) << 3)); }
__device__ __forceinline__ int sw128(int r, int c) { return r * 128 + (c ^ ((r & 7) << 3)); }
__device__ __forceinline__ int sw256(int r, int c) { return r * 256 + (c ^ ((r & 7) << 3)); }

// ---------------- CSR build: 2-phase bucket sort ----------------
// tmp entries are u32-packed: s (19 bits) | (d & 2047) << 19

__global__ void k_zero256(int* __restrict__ gcount) {
    gcount[threadIdx.x] = 0;
}

__global__ __launch_bounds__(1024) void k_binA(const int* __restrict__ eidx,
                                               unsigned* __restrict__ tmp,
                                               int* __restrict__ gcount) {
    __shared__ int acnt[NBUCK];
    __shared__ int abase[NBUCK];
    __shared__ uint2 ed[8192];
    const int t = threadIdx.x;
    if (t < NBUCK) acnt[t] = 0;
    __syncthreads();
    const int e0 = blockIdx.x * 8192;
#pragma unroll
    for (int r = 0; r < 8; ++r) {
        int e = e0 + r * 1024 + t;
        int s = __builtin_nontemporal_load(&eidx[e]);
        int d = __builtin_nontemporal_load(&eidx[NEDGE + e]);
        ed[r * 1024 + t] = make_uint2((unsigned)s, (unsigned)d);
        atomicAdd(&acnt[d >> 11], 1);
    }
    __syncthreads();
    if (t < NBUCK) {
        abase[t] = atomicAdd(&gcount[t], acnt[t]);
        acnt[t] = 0;                       // reuse as local cursor
    }
    __syncthreads();
#pragma unroll
    for (int r = 0; r < 8; ++r) {
        uint2 sd = ed[r * 1024 + t];
        int b = sd.y >> 11;
        int slot = abase[b] + atomicAdd(&acnt[b], 1);
        tmp[(size_t)b * BCAP + slot] = sd.x | ((sd.y & 2047u) << 19);
    }
}

__global__ void k_scanB(const int* __restrict__ gcount, int* __restrict__ bbase,
                        int* __restrict__ rowptr) {
    __shared__ int sd[NBUCK];
    int t = threadIdx.x;
    int v = gcount[t];
    sd[t] = v; __syncthreads();
    for (int o = 1; o < NBUCK; o <<= 1) {
        int u = (t >= o) ? sd[t - o] : 0;
        __syncthreads();
        sd[t] += u;
        __syncthreads();
    }
    bbase[t] = sd[t] - v;                  // exclusive
    if (t == 0) rowptr[NN] = NEDGE;
}

__global__ __launch_bounds__(1024) void k_binB(const unsigned* __restrict__ tmp,
                                               const int* __restrict__ gcount,
                                               const int* __restrict__ bbase,
                                               int* __restrict__ rowptr,
                                               float* __restrict__ dinv,
                                               int* __restrict__ srcs) {
    __shared__ int A[2048];
    __shared__ int B[2048];
    __shared__ int lcur[2048];
    const int t = threadIdx.x;
    const int b = blockIdx.x;
    const int nb = gcount[b];
    const int base = bbase[b];
    const unsigned* te = tmp + (size_t)b * BCAP;

    A[t] = 0; A[t + 1024] = 0;
    __syncthreads();
    for (int i = t; i < nb; i += 1024)
        atomicAdd(&A[__builtin_nontemporal_load(&te[i]) >> 19], 1);
    __syncthreads();

    {
        int n0 = (b << 11) + t;
        dinv[n0] = rsqrtf(1.f + (float)A[t]);
        dinv[n0 + 1024] = rsqrtf(1.f + (float)A[t + 1024]);
    }

    int* src = A; int* dst = B;
    for (int o = 1; o < 2048; o <<= 1) {
        for (int j = t; j < 2048; j += 1024) {
            int v = src[j];
            if (j >= o) v += src[j - o];
            dst[j] = v;
        }
        __syncthreads();
        int* tp = src; src = dst; dst = tp;
    }
    for (int j = t; j < 2048; j += 1024) {
        int excl = (j == 0) ? 0 : src[j - 1];
        int gpos = base + excl;
        rowptr[(b << 11) + j] = gpos;
        lcur[j] = gpos;
    }
    __syncthreads();

    for (int i = t; i < nb; i += 1024) {
        unsigned v = __builtin_nontemporal_load(&te[i]);
        int pos = atomicAdd(&lcur[v >> 19], 1);
        srcs[pos] = (int)(v & 0x7FFFFu);
    }
}

// ---------------- hs0 = dinv * (syn*eW + eb)  (+ zero pad rows) ----------
__global__ void k_hs0(const float* __restrict__ syn, const float* __restrict__ dinv,
                      const float* __restrict__ embW, const float* __restrict__ embB,
                      unsigned short* __restrict__ hsA, unsigned short* __restrict__ hsB) {
    int idx = blockIdx.x * 256 + threadIdx.x;     // one per 4 elems
    int n = idx >> 4, f4 = (idx & 15) * 4;
    if (n > NN) return;
    if (n == NN) {                                // zero pad row (both buffers)
        *(ushort4*)(hsA + (size_t)NN * 64 + f4) = make_ushort4(0, 0, 0, 0);
        *(ushort4*)(hsB + (size_t)NN * 64 + f4) = make_ushort4(0, 0, 0, 0);
        return;
    }
    float s = syn[n], dn = dinv[n];
    float4 ew = *(const float4*)(embW + f4);
    float4 eb = *(const float4*)(embB + f4);
    ushort4 o;
    o.x = f2b(dn * (s * ew.x + eb.x));
    o.y = f2b(dn * (s * ew.y + eb.y));
    o.z = f2b(dn * (s * ew.z + eb.z));
    o.w = f2b(dn * (s * ew.w + eb.w));
    *(ushort4*)(hsA + (size_t)n * 64 + f4) = o;
}

// ---------------- merged weight transpose (all 6 weights, x3 iters) ----------
__global__ void k_trans_all(const float* __restrict__ gcnW, const float* __restrict__ rW1,
                            const float* __restrict__ rW2, const float* __restrict__ hW1,
                            const float* __restrict__ hW2, const float* __restrict__ hW3,
                            unsigned short* __restrict__ gcnWt, unsigned short* __restrict__ rW1t,
                            unsigned short* __restrict__ rW2t, unsigned short* __restrict__ hW1t,
                            unsigned short* __restrict__ hW2t, unsigned short* __restrict__ hW3t) {
    int o = blockIdx.x * 256 + threadIdx.x;
    const float* W; unsigned short* Wt; int K, M, base;
    if      (o < 12288)  { W = gcnW; Wt = gcnWt; K = 64;  M = 64;  base = 0; }
    else if (o < 61440)  { W = rW1;  Wt = rW1t;  K = 64;  M = 256; base = 12288; }
    else if (o < 110592) { W = rW2;  Wt = rW2t;  K = 256; M = 64;  base = 61440; }
    else if (o < 503808) { W = hW1;  Wt = hW1t;  K = 512; M = 256; base = 110592; }
    else if (o < 602112) { W = hW2;  Wt = hW2t;  K = 256; M = 128; base = 503808; }
    else if (o < 605568) { W = hW3;  Wt = hW3t;  K = 128; M = 9;   base = 602112; }
    else return;
    int rel = o - base;
    int km = K * M;
    int it = rel / km;
    int rem = rel - it * km;
    int m = rem / K;
    int k = rem - m * K;
    Wt[rel] = f2b(W[(size_t)it * km + (size_t)k * M + m]);
}

// =====================================================================
// Swapped MFMA orientation: A = weights (m = out-col), B = activations
// (n = out-row).  C: lane holds m=(l>>4)*4+r (4 consecutive out-cols), n=l&15.
// =====================================================================

// ---------------- fused gather + GCN + refine ----------------
// agg[n] = dinv[n] * (hs[n] + sum_{s in N(n)} hs[s]),  hs = dinv*h (bf16).
// h is a write-once/read-once stream -> NON-TEMPORAL stores (keep hs L3-hot).

__global__ __launch_bounds__(256, 6) void k_gcnref(
    const int* __restrict__ rowptr, const int* __restrict__ srcs,
    const float* __restrict__ dinv,
    const unsigned short* __restrict__ hsin,
    const unsigned short* __restrict__ Wgt, const float* __restrict__ bg,
    const unsigned short* __restrict__ W1t, const float* __restrict__ b1,
    const unsigned short* __restrict__ W2t, const float* __restrict__ b2,
    unsigned short* __restrict__ hout, unsigned short* __restrict__ hsout)
{
    __shared__ unsigned short tl[64 * 64];    // agg -> h' -> h_out staging
    __shared__ unsigned short zl[64 * 64];    // z quarter-tile
    const int tid = threadIdx.x, wid = tid >> 6, l = tid & 63;
    const int lr = l & 15, lkq = l >> 4;
    const int g = l >> 4, i = l & 15;         // gather roles
    const int rowBase = blockIdx.x * 64;
    const int nb = rowBase + wid * 16;

    // ---- gather: 4 quads of 4 nodes; group g owns node quad*4+g ----
    for (int q = 0; q < 4; ++q) {
        const int node = nb + q * 4 + g;
        int beg = rowptr[node];
        int deg = rowptr[node + 1] - beg;
        int sl = (i < deg) ? srcs[beg + i] : NN;   // pad -> zero row

        float dn = dinv[node];
        ushort4 sv = *(const ushort4*)(hsin + (size_t)node * 64 + i * 4);
        float a0 = b2f(sv.x), a1 = b2f(sv.y), a2 = b2f(sv.z), a3 = b2f(sv.w);

        int dmax = max(max(__shfl(deg, 0), __shfl(deg, 16)),
                       max(__shfl(deg, 32), __shfl(deg, 48)));
        int dfast = dmax < 16 ? dmax : 16;

        // unroll-8: 8 row-loads in flight per lane, pure row-sum
        for (int p = 0; p < dfast; p += 8) {
            int s[8];
#pragma unroll
            for (int u = 0; u < 8; ++u)
                s[u] = __shfl(sl, (l & 48) + p + u);
            ushort4 v[8];
#pragma unroll
            for (int u = 0; u < 8; ++u)
                v[u] = *(const ushort4*)(hsin + (size_t)s[u] * 64 + i * 4);
#pragma unroll
            for (int u = 0; u < 8; ++u) {
                a0 += b2f(v[u].x); a1 += b2f(v[u].y);
                a2 += b2f(v[u].z); a3 += b2f(v[u].w);
            }
        }
        if (deg > 16) {                         // vanishingly rare tail (group-uniform)
            for (int t = 16; t < deg; ++t) {
                int st = srcs[beg + t];
                ushort4 v = *(const ushort4*)(hsin + (size_t)st * 64 + i * 4);
                a0 += b2f(v.x); a1 += b2f(v.y); a2 += b2f(v.z); a3 += b2f(v.w);
            }
        }
        ushort4 o;
        o.x = f2b(a0 * dn); o.y = f2b(a1 * dn);
        o.z = f2b(a2 * dn); o.w = f2b(a3 * dn);
        *(ushort4*)&tl[sw64(wid * 16 + q * 4 + g, i * 4)] = o;
    }
    // no barrier: GCN below reads only this wave's own 16 rows

    // ---- GCN: h' = relu(agg @ Wg + bg); wave computes its own 16 rows ----
    f32x4 ag[4];
#pragma unroll
    for (int mg = 0; mg < 4; ++mg) ag[mg] = (f32x4){0.f, 0.f, 0.f, 0.f};
#pragma unroll
    for (int kc = 0; kc < 64; kc += 32) {
        bf16x8 bfr = *(const bf16x8*)&tl[sw64(wid * 16 + lr, kc + lkq * 8)];
#pragma unroll
        for (int mg = 0; mg < 4; ++mg) {
            bf16x8 a = *(const bf16x8*)(Wgt + (size_t)(mg * 16 + lr) * 64 + kc + lkq * 8);
            ag[mg] = __builtin_amdgcn_mfma_f32_16x16x32_bf16(a, bfr, ag[mg], 0, 0, 0);
        }
    }
#pragma unroll
    for (int mg = 0; mg < 4; ++mg) {
        int m0 = mg * 16 + lkq * 4;
        float4 bb = *(const float4*)(bg + m0);
        ushort4 o;
        o.x = f2b(frelu(ag[mg][0] + bb.x));
        o.y = f2b(frelu(ag[mg][1] + bb.y));
        o.z = f2b(frelu(ag[mg][2] + bb.z));
        o.w = f2b(frelu(ag[mg][3] + bb.w));
        *(ushort4*)&tl[sw64(wid * 16 + lr, m0)] = o;   // overwrite own rows with h'
    }
    __syncthreads();

    // ---- refine in four 64-col quarters; r2 accumulates across quarters ----
    f32x4 r2[4];
#pragma unroll
    for (int mg = 0; mg < 4; ++mg) r2[mg] = (f32x4){0.f, 0.f, 0.f, 0.f};

#pragma unroll
    for (int qt = 0; qt < 4; ++qt) {
        f32x4 z1a[4];
#pragma unroll
        for (int ng = 0; ng < 4; ++ng) z1a[ng] = (f32x4){0.f, 0.f, 0.f, 0.f};
#pragma unroll
        for (int kc = 0; kc < 64; kc += 32) {
            bf16x8 a = *(const bf16x8*)(W1t +
                (size_t)(qt * 64 + wid * 16 + lr) * 64 + kc + lkq * 8);
#pragma unroll
            for (int ng = 0; ng < 4; ++ng) {
                bf16x8 bfr = *(const bf16x8*)&tl[sw64(ng * 16 + lr, kc + lkq * 8)];
                z1a[ng] = __builtin_amdgcn_mfma_f32_16x16x32_bf16(a, bfr, z1a[ng], 0, 0, 0);
            }
        }
        {
            int m0 = wid * 16 + lkq * 4;                 // local col within quarter
            float4 bb = *(const float4*)(b1 + qt * 64 + m0);
#pragma unroll
            for (int ng = 0; ng < 4; ++ng) {
                int n = ng * 16 + lr;
                ushort4 o;
                o.x = f2b(frelu(z1a[ng][0] + bb.x));
                o.y = f2b(frelu(z1a[ng][1] + bb.y));
                o.z = f2b(frelu(z1a[ng][2] + bb.z));
                o.w = f2b(frelu(z1a[ng][3] + bb.w));
                *(ushort4*)&zl[sw64(n, m0)] = o;
            }
        }
        __syncthreads();

#pragma unroll
        for (int kc = 0; kc < 64; kc += 32) {
            bf16x8 bz = *(const bf16x8*)&zl[sw64(wid * 16 + lr, kc + lkq * 8)];
#pragma unroll
            for (int mg = 0; mg < 4; ++mg) {
                bf16x8 a = *(const bf16x8*)(W2t +
                    (size_t)(mg * 16 + lr) * 256 + qt * 64 + kc + lkq * 8);
                r2[mg] = __builtin_amdgcn_mfma_f32_16x16x32_bf16(a, bz, r2[mg], 0, 0, 0);
            }
        }
        if (qt < 3) __syncthreads();   // before next quarter overwrites zl
    }

    // ---- epilogue: h = relu(h' + r + b2) -> stage in tl, then full-line copy ----
    {
        int n = wid * 16 + lr;
#pragma unroll
        for (int mg = 0; mg < 4; ++mg) {
            int m0 = mg * 16 + lkq * 4;
            float4 bb = *(const float4*)(b2 + m0);
            ushort4 rs = *(const ushort4*)&tl[sw64(n, m0)];
            ushort4 o;
            o.x = f2b(frelu(r2[mg][0] + bb.x + b2f(rs.x)));
            o.y = f2b(frelu(r2[mg][1] + bb.y + b2f(rs.y)));
            o.z = f2b(frelu(r2[mg][2] + bb.z + b2f(rs.z)));
            o.w = f2b(frelu(r2[mg][3] + bb.w + b2f(rs.w)));
            *(ushort4*)&tl[sw64(n, m0)] = o;
        }
    }
    __syncthreads();
    {
        int r = tid >> 2, c16 = (tid & 3) * 16;     // full 128B lines per 4 threads
        bf16x8 v0 = *(const bf16x8*)&tl[sw64(r, c16)];
        bf16x8 v1 = *(const bf16x8*)&tl[sw64(r, c16 + 8)];
        // h is streaming (read once by head) -> non-temporal, keep L3 for hs
        __builtin_nontemporal_store(v0, (bf16x8*)(hout + (size_t)(rowBase + r) * 64 + c16));
        __builtin_nontemporal_store(v1, (bf16x8*)(hout + (size_t)(rowBase + r) * 64 + c16 + 8));
        if (hsout) {                                 // hs = h * dinv (for next gather)
            float dv = dinv[rowBase + r];
            bf16x8 w0, w1;
#pragma unroll
            for (int j = 0; j < 8; ++j) {
                w0[j] = (short)f2b(b2f((unsigned short)v0[j]) * dv);
                w1[j] = (short)f2b(b2f((unsigned short)v1[j]) * dv);
            }
            *(bf16x8*)(hsout + (size_t)(rowBase + r) * 64 + c16) = w0;
            *(bf16x8*)(hsout + (size_t)(rowBase + r) * 64 + c16 + 8) = w1;
        }
    }
}

// ---------------- fused head: out = sig(relu(relu(hall@W1)@W2)@W3) ----------
// hall read ONCE (non-temporal), full-K z1; LDS 32KB (z1 sw256, z2 overlaid).
__global__ __launch_bounds__(256, 4) void k_head(
    const unsigned short* __restrict__ hb,   // [NB][512]
    const unsigned short* __restrict__ W1t,  // [256][512]
    const float* __restrict__ b1,
    const unsigned short* __restrict__ W2t,  // [128][256]
    const float* __restrict__ b2,
    const unsigned short* __restrict__ W3t,  // [9][128]
    const float* __restrict__ b3,
    float* __restrict__ out)
{
    __shared__ unsigned short sm[64 * 256];  // z1 (sw256); later z2 (sw128)
    const int tid = threadIdx.x, wid = tid >> 6, l = tid & 63;
    const int lr = l & 15, lkq = l >> 4;
    const unsigned short* hall = hb + (size_t)blockIdx.x * 64 * 512;

    f32x4 acc1[4][4];
#pragma unroll
    for (int mg = 0; mg < 4; ++mg)
#pragma unroll
        for (int ng = 0; ng < 4; ++ng) acc1[mg][ng] = (f32x4){0.f, 0.f, 0.f, 0.f};

    for (int kc = 0; kc < 512; kc += 32) {
        bf16x8 bfr[4];
#pragma unroll
        for (int ng = 0; ng < 4; ++ng)
            bfr[ng] = __builtin_nontemporal_load(
                (const bf16x8*)(hall + (size_t)(ng * 16 + lr) * 512 + kc + lkq * 8));
#pragma unroll
        for (int mg = 0; mg < 4; ++mg) {
            bf16x8 a = *(const bf16x8*)(W1t + (size_t)(wid * 64 + mg * 16 + lr) * 512 + kc + lkq * 8);
#pragma unroll
            for (int ng = 0; ng < 4; ++ng)
                acc1[mg][ng] = __builtin_amdgcn_mfma_f32_16x16x32_bf16(a, bfr[ng], acc1[mg][ng], 0, 0, 0);
        }
    }
#pragma unroll
    for (int mg = 0; mg < 4; ++mg) {
        int m0 = wid * 64 + mg * 16 + lkq * 4;
        float4 bb = *(const float4*)(b1 + m0);
#pragma unroll
        for (int ng = 0; ng < 4; ++ng) {
            int n = ng * 16 + lr;
            ushort4 o;
            o.x = f2b(frelu(acc1[mg][ng][0] + bb.x));
            o.y = f2b(frelu(acc1[mg][ng][1] + bb.y));
            o.z = f2b(frelu(acc1[mg][ng][2] + bb.z));
            o.w = f2b(frelu(acc1[mg][ng][3] + bb.w));
            *(ushort4*)&sm[sw256(n, m0)] = o;
        }
    }
    __syncthreads();

    f32x4 acc2[2][4];
#pragma unroll
    for (int mg = 0; mg < 2; ++mg)
#pragma unroll
        for (int ng = 0; ng < 4; ++ng) acc2[mg][ng] = (f32x4){0.f, 0.f, 0.f, 0.f};
#pragma unroll
    for (int kc = 0; kc < 256; kc += 32) {
        bf16x8 bfr[4];
#pragma unroll
        for (int ng = 0; ng < 4; ++ng)
            bfr[ng] = *(const bf16x8*)&sm[sw256(ng * 16 + lr, kc + lkq * 8)];
#pragma unroll
        for (int mg = 0; mg < 2; ++mg) {
            bf16x8 a = *(const bf16x8*)(W2t + (size_t)(wid * 32 + mg * 16 + lr) * 256 + kc + lkq * 8);
#pragma unroll
            for (int ng = 0; ng < 4; ++ng)
                acc2[mg][ng] = __builtin_amdgcn_mfma_f32_16x16x32_bf16(a, bfr[ng], acc2[mg][ng], 0, 0, 0);
        }
    }
    __syncthreads();   // all z1 reads done before overwriting sm with z2

#pragma unroll
    for (int mg = 0; mg < 2; ++mg) {
        int m0 = wid * 32 + mg * 16 + lkq * 4;
        float4 bb = *(const float4*)(b2 + m0);
#pragma unroll
        for (int ng = 0; ng < 4; ++ng) {
            int n = ng * 16 + lr;
            ushort4 o;
            o.x = f2b(frelu(acc2[mg][ng][0] + bb.x));
            o.y = f2b(frelu(acc2[mg][ng][1] + bb.y));
            o.z = f2b(frelu(acc2[mg][ng][2] + bb.z));
            o.w = f2b(frelu(acc2[mg][ng][3] + bb.w));
            *(ushort4*)&sm[sw128(n, m0)] = o;
        }
    }
    __syncthreads();

    f32x4 a3 = (f32x4){0.f, 0.f, 0.f, 0.f};
    int arow = lr < 9 ? lr : 8;
#pragma unroll
    for (int kc = 0; kc < 128; kc += 32) {
        bf16x8 bz = *(const bf16x8*)&sm[sw128(wid * 16 + lr, kc + lkq * 8)];
        bf16x8 a = *(const bf16x8*)(W3t + (size_t)arow * 128 + kc + lkq * 8);
        a3 = __builtin_amdgcn_mfma_f32_16x16x32_bf16(a, bz, a3, 0, 0, 0);
    }
    {
        long shot = (long)blockIdx.x * 64 + wid * 16 + lr;
#pragma unroll
        for (int r = 0; r < 4; ++r) {
            int m = lkq * 4 + r;
            if (m < 9) out[shot * 9 + m] = 1.f / (1.f + expf(-(a3[r] + b3[m])));
        }
    }
}

// ---------------- launcher ----------------
// Workspace (~215 MB): h 67 | hsA 67 | hsB 67 (tmp 16.8 aliased) | srcs 8.4 |
// rowptr 2.1 | dinv 2.1 | gcount/bbase | Wt 1.2

extern "C" void kernel_launch(void* const* d_in, const int* in_sizes, int n_in,
                              void* d_out, int out_size, void* d_ws, size_t ws_size,
                              hipStream_t stream) {
    const float* syn  = (const float*)d_in[0];
    const int*   eidx = (const int*)d_in[1];
    const float* embW = (const float*)d_in[3];
    const float* embB = (const float*)d_in[4];
    const float* gcnW = (const float*)d_in[5];
    const float* gcnB = (const float*)d_in[6];
    const float* rW1  = (const float*)d_in[7];
    const float* rB1  = (const float*)d_in[8];
    const float* rW2  = (const float*)d_in[9];
    const float* rB2  = (const float*)d_in[10];
    const float* hW1  = (const float*)d_in[11];
    const float* hB1  = (const float*)d_in[12];
    const float* hW2  = (const float*)d_in[13];
    const float* hB2  = (const float*)d_in[14];
    const float* hW3  = (const float*)d_in[15];
    const float* hB3  = (const float*)d_in[16];
    float* out = (float*)d_out;

    unsigned short* h      = (unsigned short*)d_ws;
    unsigned short* hsA    = h + (size_t)NN * 64;
    unsigned short* hsB    = hsA + (size_t)NN * 64 + 64;
    int*            srcs   = (int*)(hsB + (size_t)NN * 64 + 64);
    int*            rowptr = srcs + NEDGE;                 // NN+1 (+pad)
    float*          dinv   = (float*)(rowptr + NN + 16);
    int*            gcount = (int*)(dinv + NN);
    int*            bbase  = gcount + NBUCK;
    unsigned short* gcnWt  = (unsigned short*)(bbase + NBUCK + 16);
    unsigned short* rW1t   = gcnWt + 3 * 64 * 64;
    unsigned short* rW2t   = rW1t + 3 * 64 * 256;
    unsigned short* hW1t   = rW2t + 3 * 256 * 64;
    unsigned short* hW2t   = hW1t + 3 * 512 * 256;
    unsigned short* hW3t   = hW2t + 3 * 256 * 128;
    unsigned*       tmp    = (unsigned*)hsB;               // alias: dead before hsB use

    // weights + CSR build
    k_trans_all<<<(605568 + 255) / 256, 256, 0, stream>>>(
        gcnW, rW1, rW2, hW1, hW2, hW3, gcnWt, rW1t, rW2t, hW1t, hW2t, hW3t);
    k_zero256<<<1, NBUCK, 0, stream>>>(gcount);
    k_binA<<<NEDGE / 8192, 1024, 0, stream>>>(eidx, tmp, gcount);
    k_scanB<<<1, NBUCK, 0, stream>>>(gcount, bbase, rowptr);
    k_binB<<<NBUCK, 1024, 0, stream>>>(tmp, gcount, bbase, rowptr, dinv, srcs);
    k_hs0<<<((NN + 1) * 16 + 255) / 256, 256, 0, stream>>>(syn, dinv, embW, embB, hsA, hsB);

    for (int i = 0; i < NITERS; ++i) {
        unsigned short* hsin  = (i & 1) ? hsB : hsA;
        unsigned short* hsout = (i == 2) ? nullptr : ((i & 1) ? hsA : hsB);
        k_gcnref<<<NN / 64, 256, 0, stream>>>(
            rowptr, srcs, dinv, hsin,
            gcnWt + (size_t)i * 64 * 64, gcnB + (size_t)i * 64,
            rW1t + (size_t)i * 64 * 256, rB1 + (size_t)i * 256,
            rW2t + (size_t)i * 256 * 64, rB2 + (size_t)i * 64,
            h, hsout);
        k_head<<<NB / 64, 256, 0, stream>>>(
            h,
            hW1t + (size_t)i * 512 * 256, hB1 + (size_t)i * 256,
            hW2t + (size_t)i * 256 * 128, hB2 + (size_t)i * 128,
            hW3t + (size_t)i * 128 * 9,   hB3 + (size_t)i * 9,
            out + (size_t)i * NB * NQ);
    }
}

// Round 16
// 1000.737 us; speedup vs baseline: 1.0795x; 1.0795x over previous
//
#include <hip/hip_runtime.h>
#include <cstdint>

#define NN 524288       // total nodes = B*S
#define NB 65536        // batch
#define NQ 9
#define NEDGE 2097152
#define NITERS 3
#define NBUCK 256       // dst-buckets (2048 nodes each)
#define BCAP 16384      // slots per bucket (expected 8192, 2x headroom)

typedef __attribute__((ext_vector_type(8))) short bf16x8;
typedef __attribute__((ext_vector_type(4))) float f32x4;

// ---------------- bf16 helpers (bit-level, RNE) ----------------
__device__ __forceinline__ unsigned short f2b(float f) {
    union { float f; unsigned u; } v; v.f = f;
    unsigned u = v.u;
    u += 0x7FFFu + ((u >> 16) & 1u);
    return (unsigned short)(u >> 16);
}
__device__ __forceinline__ float b2f(unsigned short b) {
    union { unsigned u; float f; } v; v.u = ((unsigned)b) << 16;
    return v.f;
}
__device__ __forceinline__ float frelu(float v) { return v > 0.f ? v : 0.f; }

// Swizzled LDS index (ushort units): XOR row&7 into ushort-col bits 3..5.
__device__ __forceinline__ int sw64(int r, int c)  { return r * 64  + (c ^ ((r & 7) << 3)); }
__device__ __forceinline__ int sw128(int r, int c) { return r * 128 + (c ^ ((r & 7) << 3)); }
__device__ __forceinline__ int sw256(int r, int c) { return r * 256 + (c ^ ((r & 7) << 3)); }

// ---------------- CSR build: 2-phase bucket sort ----------------

__global__ void k_zero256(int* __restrict__ gcount) {
    gcount[threadIdx.x] = 0;
}

// Phase A: bin edges by dst-bucket into per-bucket staging regions.
__global__ __launch_bounds__(1024) void k_binA(const int* __restrict__ eidx,
                                               uint2* __restrict__ tmp,
                                               int* __restrict__ gcount) {
    __shared__ int acnt[NBUCK];
    __shared__ int abase[NBUCK];
    __shared__ uint2 ed[8192];
    const int t = threadIdx.x;
    if (t < NBUCK) acnt[t] = 0;
    __syncthreads();
    const int e0 = blockIdx.x * 8192;
#pragma unroll
    for (int r = 0; r < 8; ++r) {
        int e = e0 + r * 1024 + t;
        int s = eidx[e], d = eidx[NEDGE + e];
        ed[r * 1024 + t] = make_uint2((unsigned)s, (unsigned)d);
        atomicAdd(&acnt[d >> 11], 1);
    }
    __syncthreads();
    if (t < NBUCK) {
        abase[t] = atomicAdd(&gcount[t], acnt[t]);
        acnt[t] = 0;                       // reuse as local cursor
    }
    __syncthreads();
#pragma unroll
    for (int r = 0; r < 8; ++r) {
        uint2 sd = ed[r * 1024 + t];
        int b = sd.y >> 11;
        int slot = abase[b] + atomicAdd(&acnt[b], 1);
        tmp[(size_t)b * BCAP + slot] = sd;
    }
}

// Scan of bucket totals -> bucket bases.  1 block x 256.
__global__ void k_scanB(const int* __restrict__ gcount, int* __restrict__ bbase,
                        int* __restrict__ rowptr) {
    __shared__ int sd[NBUCK];
    int t = threadIdx.x;
    int v = gcount[t];
    sd[t] = v; __syncthreads();
    for (int o = 1; o < NBUCK; o <<= 1) {
        int u = (t >= o) ? sd[t - o] : 0;
        __syncthreads();
        sd[t] += u;
        __syncthreads();
    }
    bbase[t] = sd[t] - v;                  // exclusive
    if (t == 0) rowptr[NN] = NEDGE;
}

// Phase B: per bucket (2048 nodes): LDS histogram -> dinv, LDS scan ->
// rowptr slice, LDS-cursor counting-sort fill of srcs (L2-local writes).
__global__ __launch_bounds__(1024) void k_binB(const uint2* __restrict__ tmp,
                                               const int* __restrict__ gcount,
                                               const int* __restrict__ bbase,
                                               int* __restrict__ rowptr,
                                               float* __restrict__ dinv,
                                               int* __restrict__ srcs) {
    __shared__ int A[2048];
    __shared__ int B[2048];
    __shared__ int lcur[2048];
    const int t = threadIdx.x;
    const int b = blockIdx.x;
    const int nb = gcount[b];
    const int base = bbase[b];
    const uint2* te = tmp + (size_t)b * BCAP;

    A[t] = 0; A[t + 1024] = 0;
    __syncthreads();
    for (int i = t; i < nb; i += 1024)
        atomicAdd(&A[te[i].y & 2047], 1);
    __syncthreads();

    // dinv = rsqrt(1 + deg)
    {
        int n0 = (b << 11) + t;
        dinv[n0] = rsqrtf(1.f + (float)A[t]);
        dinv[n0 + 1024] = rsqrtf(1.f + (float)A[t + 1024]);
    }

    // inclusive Hillis-Steele scan over 2048 (ping-pong A/B)
    int* src = A; int* dst = B;
    for (int o = 1; o < 2048; o <<= 1) {
        for (int j = t; j < 2048; j += 1024) {
            int v = src[j];
            if (j >= o) v += src[j - o];
            dst[j] = v;
        }
        __syncthreads();
        int* tp = src; src = dst; dst = tp;
    }
    for (int j = t; j < 2048; j += 1024) {
        int excl = (j == 0) ? 0 : src[j - 1];
        int gpos = base + excl;
        rowptr[(b << 11) + j] = gpos;
        lcur[j] = gpos;
    }
    __syncthreads();

    for (int i = t; i < nb; i += 1024) {
        uint2 sd = te[i];
        int pos = atomicAdd(&lcur[sd.y & 2047], 1);
        srcs[pos] = (int)sd.x;
    }
}

// ---------------- merged weight transpose (all 6 weights, x3 iters) ----------
__global__ void k_trans_all(const float* __restrict__ gcnW, const float* __restrict__ rW1,
                            const float* __restrict__ rW2, const float* __restrict__ hW1,
                            const float* __restrict__ hW2, const float* __restrict__ hW3,
                            unsigned short* __restrict__ gcnWt, unsigned short* __restrict__ rW1t,
                            unsigned short* __restrict__ rW2t, unsigned short* __restrict__ hW1t,
                            unsigned short* __restrict__ hW2t, unsigned short* __restrict__ hW3t) {
    int o = blockIdx.x * 256 + threadIdx.x;
    const float* W; unsigned short* Wt; int K, M, base;
    if      (o < 12288)  { W = gcnW; Wt = gcnWt; K = 64;  M = 64;  base = 0; }
    else if (o < 61440)  { W = rW1;  Wt = rW1t;  K = 64;  M = 256; base = 12288; }
    else if (o < 110592) { W = rW2;  Wt = rW2t;  K = 256; M = 64;  base = 61440; }
    else if (o < 503808) { W = hW1;  Wt = hW1t;  K = 512; M = 256; base = 110592; }
    else if (o < 602112) { W = hW2;  Wt = hW2t;  K = 256; M = 128; base = 503808; }
    else if (o < 605568) { W = hW3;  Wt = hW3t;  K = 128; M = 9;   base = 602112; }
    else return;
    int rel = o - base;
    int km = K * M;
    int it = rel / km;
    int rem = rel - it * km;
    int m = rem / K;
    int k = rem - m * K;
    Wt[rel] = f2b(W[(size_t)it * km + (size_t)k * M + m]);
}

// =====================================================================
// Swapped MFMA orientation: A = weights (m = out-col), B = activations
// (n = out-row).  A-frag: Wt[m=base+l&15][kc+(l>>4)*8..+8] row-contig.
// B-frag: act[n=base+l&15][kc+(l>>4)*8..+8] row-contig.
// C: lane holds m=(l>>4)*4+r (4 consecutive out-cols), n=l&15.
// =====================================================================

// ---------------- fused gather + GCN + refine (+ embed for iter 0) --------
// Block = 64 nodes.  LDS: tl 8KB + zl 8KB = 16KB.  launch_bounds(256,6)
// [r9/r12-verified optimum; 8 blocks/CU thrashes L2 (r11)].

template<bool EMBED>
__global__ __launch_bounds__(256, 6) void k_gcnref(
    const int* __restrict__ rowptr, const int* __restrict__ srcs,
    const float* __restrict__ dinv,
    const float* __restrict__ syn, const float* __restrict__ embW,
    const float* __restrict__ embB,
    const unsigned short* __restrict__ hin,
    const unsigned short* __restrict__ Wgt, const float* __restrict__ bg,
    const unsigned short* __restrict__ W1t, const float* __restrict__ b1,
    const unsigned short* __restrict__ W2t, const float* __restrict__ b2,
    unsigned short* __restrict__ hout)
{
    __shared__ unsigned short tl[64 * 64];    // agg -> h' -> h_out staging
    __shared__ unsigned short zl[64 * 64];    // z quarter-tile
    const int tid = threadIdx.x, wid = tid >> 6, l = tid & 63;
    const int lr = l & 15, lkq = l >> 4;
    const int g = l >> 4, i = l & 15;         // gather roles
    const int rowBase = blockIdx.x * 64;
    const int nb = rowBase + wid * 16;

    float4 ew4, eb4;
    if (EMBED) {
        ew4 = *(const float4*)(embW + i * 4);
        eb4 = *(const float4*)(embB + i * 4);
    }

    // ---- gather: 4 quads of 4 nodes; group g owns node quad*4+g ----
    for (int q = 0; q < 4; ++q) {
        const int node = nb + q * 4 + g;
        int beg = rowptr[node];
        int deg = rowptr[node + 1] - beg;
        int   sl = (i < deg) ? srcs[beg + i] : node;   // pad: self, weight 0
        float wl = (i < deg) ? dinv[sl] : 0.f;

        float dn = dinv[node];
        float a0, a1, a2, a3;
        if (EMBED) {
            float s0 = syn[node];
            a0 = (s0 * ew4.x + eb4.x) * dn;
            a1 = (s0 * ew4.y + eb4.y) * dn;
            a2 = (s0 * ew4.z + eb4.z) * dn;
            a3 = (s0 * ew4.w + eb4.w) * dn;
        } else {
            ushort4 sv = *(const ushort4*)(hin + (size_t)node * 64 + i * 4);
            a0 = b2f(sv.x) * dn; a1 = b2f(sv.y) * dn;
            a2 = b2f(sv.z) * dn; a3 = b2f(sv.w) * dn;
        }

        int dmax = max(max(__shfl(deg, 0), __shfl(deg, 16)),
                       max(__shfl(deg, 32), __shfl(deg, 48)));
        int dfast = dmax < 16 ? dmax : 16;

        // unroll-8: 8 row-loads in flight per lane
        for (int p = 0; p < dfast; p += 8) {
            int   s[8]; float w[8];
#pragma unroll
            for (int u = 0; u < 8; ++u) {
                int idx = (l & 48) + p + u;
                s[u] = __shfl(sl, idx);
                w[u] = __shfl(wl, idx);
            }
            if (EMBED) {
                float sy[8];
#pragma unroll
                for (int u = 0; u < 8; ++u) sy[u] = syn[s[u]];
#pragma unroll
                for (int u = 0; u < 8; ++u) {
                    a0 += (sy[u] * ew4.x + eb4.x) * w[u];
                    a1 += (sy[u] * ew4.y + eb4.y) * w[u];
                    a2 += (sy[u] * ew4.z + eb4.z) * w[u];
                    a3 += (sy[u] * ew4.w + eb4.w) * w[u];
                }
            } else {
                ushort4 v[8];
#pragma unroll
                for (int u = 0; u < 8; ++u)
                    v[u] = *(const ushort4*)(hin + (size_t)s[u] * 64 + i * 4);
#pragma unroll
                for (int u = 0; u < 8; ++u) {
                    a0 += b2f(v[u].x) * w[u];
                    a1 += b2f(v[u].y) * w[u];
                    a2 += b2f(v[u].z) * w[u];
                    a3 += b2f(v[u].w) * w[u];
                }
            }
        }
        if (deg > 16) {                         // vanishingly rare tail (group-uniform)
            for (int t = 16; t < deg; ++t) {
                int st = srcs[beg + t];
                float wt = dinv[st];
                if (EMBED) {
                    float sy = syn[st];
                    a0 += (sy * ew4.x + eb4.x) * wt;
                    a1 += (sy * ew4.y + eb4.y) * wt;
                    a2 += (sy * ew4.z + eb4.z) * wt;
                    a3 += (sy * ew4.w + eb4.w) * wt;
                } else {
                    ushort4 v = *(const ushort4*)(hin + (size_t)st * 64 + i * 4);
                    a0 += b2f(v.x) * wt; a1 += b2f(v.y) * wt;
                    a2 += b2f(v.z) * wt; a3 += b2f(v.w) * wt;
                }
            }
        }
        ushort4 o;
        o.x = f2b(a0 * dn); o.y = f2b(a1 * dn);
        o.z = f2b(a2 * dn); o.w = f2b(a3 * dn);
        *(ushort4*)&tl[sw64(wid * 16 + q * 4 + g, i * 4)] = o;
    }
    // no barrier: GCN below reads only this wave's own 16 rows

    // ---- GCN: h' = relu(agg @ Wg + bg); wave computes its own 16 rows ----
    f32x4 ag[4];
#pragma unroll
    for (int mg = 0; mg < 4; ++mg) ag[mg] = (f32x4){0.f, 0.f, 0.f, 0.f};
#pragma unroll
    for (int kc = 0; kc < 64; kc += 32) {
        bf16x8 bfr = *(const bf16x8*)&tl[sw64(wid * 16 + lr, kc + lkq * 8)];
#pragma unroll
        for (int mg = 0; mg < 4; ++mg) {
            bf16x8 a = *(const bf16x8*)(Wgt + (size_t)(mg * 16 + lr) * 64 + kc + lkq * 8);
            ag[mg] = __builtin_amdgcn_mfma_f32_16x16x32_bf16(a, bfr, ag[mg], 0, 0, 0);
        }
    }
#pragma unroll
    for (int mg = 0; mg < 4; ++mg) {
        int m0 = mg * 16 + lkq * 4;
        float4 bb = *(const float4*)(bg + m0);
        ushort4 o;
        o.x = f2b(frelu(ag[mg][0] + bb.x));
        o.y = f2b(frelu(ag[mg][1] + bb.y));
        o.z = f2b(frelu(ag[mg][2] + bb.z));
        o.w = f2b(frelu(ag[mg][3] + bb.w));
        *(ushort4*)&tl[sw64(wid * 16 + lr, m0)] = o;   // overwrite own rows with h'
    }
    __syncthreads();

    // ---- refine in four 64-col quarters; r2 accumulates across quarters ----
    f32x4 r2[4];
#pragma unroll
    for (int mg = 0; mg < 4; ++mg) r2[mg] = (f32x4){0.f, 0.f, 0.f, 0.f};

#pragma unroll
    for (int qt = 0; qt < 4; ++qt) {
        // R1 quarter: z cols qt*64..+64; this wave computes 16 of them
        f32x4 z1a[4];
#pragma unroll
        for (int ng = 0; ng < 4; ++ng) z1a[ng] = (f32x4){0.f, 0.f, 0.f, 0.f};
#pragma unroll
        for (int kc = 0; kc < 64; kc += 32) {
            bf16x8 a = *(const bf16x8*)(W1t +
                (size_t)(qt * 64 + wid * 16 + lr) * 64 + kc + lkq * 8);
#pragma unroll
            for (int ng = 0; ng < 4; ++ng) {
                bf16x8 bfr = *(const bf16x8*)&tl[sw64(ng * 16 + lr, kc + lkq * 8)];
                z1a[ng] = __builtin_amdgcn_mfma_f32_16x16x32_bf16(a, bfr, z1a[ng], 0, 0, 0);
            }
        }
        {
            int m0 = wid * 16 + lkq * 4;                 // local col within quarter
            float4 bb = *(const float4*)(b1 + qt * 64 + m0);
#pragma unroll
            for (int ng = 0; ng < 4; ++ng) {
                int n = ng * 16 + lr;
                ushort4 o;
                o.x = f2b(frelu(z1a[ng][0] + bb.x));
                o.y = f2b(frelu(z1a[ng][1] + bb.y));
                o.z = f2b(frelu(z1a[ng][2] + bb.z));
                o.w = f2b(frelu(z1a[ng][3] + bb.w));
                *(ushort4*)&zl[sw64(n, m0)] = o;
            }
        }
        __syncthreads();

        // R2 partial: accumulate k = qt*64 .. +64
#pragma unroll
        for (int kc = 0; kc < 64; kc += 32) {
            bf16x8 bz = *(const bf16x8*)&zl[sw64(wid * 16 + lr, kc + lkq * 8)];
#pragma unroll
            for (int mg = 0; mg < 4; ++mg) {
                bf16x8 a = *(const bf16x8*)(W2t +
                    (size_t)(mg * 16 + lr) * 256 + qt * 64 + kc + lkq * 8);
                r2[mg] = __builtin_amdgcn_mfma_f32_16x16x32_bf16(a, bz, r2[mg], 0, 0, 0);
            }
        }
        if (qt < 3) __syncthreads();   // before next quarter overwrites zl
    }

    // ---- epilogue: h = relu(h' + r + b2) -> stage in tl, then full-line copy ----
    {
        int n = wid * 16 + lr;
#pragma unroll
        for (int mg = 0; mg < 4; ++mg) {
            int m0 = mg * 16 + lkq * 4;
            float4 bb = *(const float4*)(b2 + m0);
            ushort4 rs = *(const ushort4*)&tl[sw64(n, m0)];
            ushort4 o;
            o.x = f2b(frelu(r2[mg][0] + bb.x + b2f(rs.x)));
            o.y = f2b(frelu(r2[mg][1] + bb.y + b2f(rs.y)));
            o.z = f2b(frelu(r2[mg][2] + bb.z + b2f(rs.z)));
            o.w = f2b(frelu(r2[mg][3] + bb.w + b2f(rs.w)));
            *(ushort4*)&tl[sw64(n, m0)] = o;
        }
    }
    __syncthreads();
    {
        int r = tid >> 2, c16 = (tid & 3) * 16;     // full 128B lines per 4 threads
        bf16x8 v0 = *(const bf16x8*)&tl[sw64(r, c16)];
        bf16x8 v1 = *(const bf16x8*)&tl[sw64(r, c16 + 8)];
        *(bf16x8*)(hout + (size_t)(rowBase + r) * 64 + c16) = v0;
        *(bf16x8*)(hout + (size_t)(rowBase + r) * 64 + c16 + 8) = v1;
    }
}

// ---------------- fused head: out = sig(relu(relu(hall@W1)@W2)@W3) ----------
// hall read ONCE, full-K z1; LDS 32KB (z1 [64][256] sw, z2 overlaid).
__global__ __launch_bounds__(256, 4) void k_head(
    const unsigned short* __restrict__ hb,   // [NB][512]
    const unsigned short* __restrict__ W1t,  // [256][512]
    const float* __restrict__ b1,
    const unsigned short* __restrict__ W2t,  // [128][256]
    const float* __restrict__ b2,
    const unsigned short* __restrict__ W3t,  // [9][128]
    const float* __restrict__ b3,
    float* __restrict__ out)
{
    __shared__ unsigned short sm[64 * 256];  // z1 (sw256); later z2 (sw128)
    const int tid = threadIdx.x, wid = tid >> 6, l = tid & 63;
    const int lr = l & 15, lkq = l >> 4;
    const unsigned short* hall = hb + (size_t)blockIdx.x * 64 * 512;

    f32x4 acc1[4][4];
#pragma unroll
    for (int mg = 0; mg < 4; ++mg)
#pragma unroll
        for (int ng = 0; ng < 4; ++ng) acc1[mg][ng] = (f32x4){0.f, 0.f, 0.f, 0.f};

    for (int kc = 0; kc < 512; kc += 32) {
        bf16x8 bfr[4];
#pragma unroll
        for (int ng = 0; ng < 4; ++ng)
            bfr[ng] = *(const bf16x8*)(hall + (size_t)(ng * 16 + lr) * 512 + kc + lkq * 8);
#pragma unroll
        for (int mg = 0; mg < 4; ++mg) {
            bf16x8 a = *(const bf16x8*)(W1t + (size_t)(wid * 64 + mg * 16 + lr) * 512 + kc + lkq * 8);
#pragma unroll
            for (int ng = 0; ng < 4; ++ng)
                acc1[mg][ng] = __builtin_amdgcn_mfma_f32_16x16x32_bf16(a, bfr[ng], acc1[mg][ng], 0, 0, 0);
        }
    }
#pragma unroll
    for (int mg = 0; mg < 4; ++mg) {
        int m0 = wid * 64 + mg * 16 + lkq * 4;
        float4 bb = *(const float4*)(b1 + m0);
#pragma unroll
        for (int ng = 0; ng < 4; ++ng) {
            int n = ng * 16 + lr;
            ushort4 o;
            o.x = f2b(frelu(acc1[mg][ng][0] + bb.x));
            o.y = f2b(frelu(acc1[mg][ng][1] + bb.y));
            o.z = f2b(frelu(acc1[mg][ng][2] + bb.z));
            o.w = f2b(frelu(acc1[mg][ng][3] + bb.w));
            *(ushort4*)&sm[sw256(n, m0)] = o;
        }
    }
    __syncthreads();

    f32x4 acc2[2][4];
#pragma unroll
    for (int mg = 0; mg < 2; ++mg)
#pragma unroll
        for (int ng = 0; ng < 4; ++ng) acc2[mg][ng] = (f32x4){0.f, 0.f, 0.f, 0.f};
#pragma unroll
    for (int kc = 0; kc < 256; kc += 32) {
        bf16x8 bfr[4];
#pragma unroll
        for (int ng = 0; ng < 4; ++ng)
            bfr[ng] = *(const bf16x8*)&sm[sw256(ng * 16 + lr, kc + lkq * 8)];
#pragma unroll
        for (int mg = 0; mg < 2; ++mg) {
            bf16x8 a = *(const bf16x8*)(W2t + (size_t)(wid * 32 + mg * 16 + lr) * 256 + kc + lkq * 8);
#pragma unroll
            for (int ng = 0; ng < 4; ++ng)
                acc2[mg][ng] = __builtin_amdgcn_mfma_f32_16x16x32_bf16(a, bfr[ng], acc2[mg][ng], 0, 0, 0);
        }
    }
    __syncthreads();   // all z1 reads done before overwriting sm with z2

#pragma unroll
    for (int mg = 0; mg < 2; ++mg) {
        int m0 = wid * 32 + mg * 16 + lkq * 4;
        float4 bb = *(const float4*)(b2 + m0);
#pragma unroll
        for (int ng = 0; ng < 4; ++ng) {
            int n = ng * 16 + lr;
            ushort4 o;
            o.x = f2b(frelu(acc2[mg][ng][0] + bb.x));
            o.y = f2b(frelu(acc2[mg][ng][1] + bb.y));
            o.z = f2b(frelu(acc2[mg][ng][2] + bb.z));
            o.w = f2b(frelu(acc2[mg][ng][3] + bb.w));
            *(ushort4*)&sm[sw128(n, m0)] = o;
        }
    }
    __syncthreads();

    f32x4 a3 = (f32x4){0.f, 0.f, 0.f, 0.f};
    int arow = lr < 9 ? lr : 8;
#pragma unroll
    for (int kc = 0; kc < 128; kc += 32) {
        bf16x8 bz = *(const bf16x8*)&sm[sw128(wid * 16 + lr, kc + lkq * 8)];
        bf16x8 a = *(const bf16x8*)(W3t + (size_t)arow * 128 + kc + lkq * 8);
        a3 = __builtin_amdgcn_mfma_f32_16x16x32_bf16(a, bz, a3, 0, 0, 0);
    }
    {
        long shot = (long)blockIdx.x * 64 + wid * 16 + lr;
#pragma unroll
        for (int r = 0; r < 4; ++r) {
            int m = lkq * 4 + r;
            if (m < 9) out[shot * 9 + m] = 1.f / (1.f + expf(-(a3[r] + b3[m])));
        }
    }
}

// ---------------- launcher ----------------
// Workspace (~182 MB): h0 67 | h1 67 | srcs 8.4 | rowptr 2.1 | dinv 2.1 |
// tmp 33.5 | gcount/bbase | Wt 1.2

extern "C" void kernel_launch(void* const* d_in, const int* in_sizes, int n_in,
                              void* d_out, int out_size, void* d_ws, size_t ws_size,
                              hipStream_t stream) {
    const float* syn  = (const float*)d_in[0];
    const int*   eidx = (const int*)d_in[1];
    const float* embW = (const float*)d_in[3];
    const float* embB = (const float*)d_in[4];
    const float* gcnW = (const float*)d_in[5];
    const float* gcnB = (const float*)d_in[6];
    const float* rW1  = (const float*)d_in[7];
    const float* rB1  = (const float*)d_in[8];
    const float* rW2  = (const float*)d_in[9];
    const float* rB2  = (const float*)d_in[10];
    const float* hW1  = (const float*)d_in[11];
    const float* hB1  = (const float*)d_in[12];
    const float* hW2  = (const float*)d_in[13];
    const float* hB2  = (const float*)d_in[14];
    const float* hW3  = (const float*)d_in[15];
    const float* hB3  = (const float*)d_in[16];
    float* out = (float*)d_out;

    unsigned short* h0     = (unsigned short*)d_ws;
    unsigned short* h1     = h0 + (size_t)NN * 64;
    int*            srcs   = (int*)(h1 + (size_t)NN * 64);
    int*            rowptr = srcs + NEDGE;                 // NN+1 (+pad)
    float*          dinv   = (float*)(rowptr + NN + 16);
    uint2*          tmp    = (uint2*)(dinv + NN);          // 8B-aligned by construction
    int*            gcount = (int*)(tmp + (size_t)NBUCK * BCAP);
    int*            bbase  = gcount + NBUCK;
    unsigned short* gcnWt  = (unsigned short*)(bbase + NBUCK + 16);
    unsigned short* rW1t   = gcnWt + 3 * 64 * 64;
    unsigned short* rW2t   = rW1t + 3 * 64 * 256;
    unsigned short* hW1t   = rW2t + 3 * 256 * 64;
    unsigned short* hW2t   = hW1t + 3 * 512 * 256;
    unsigned short* hW3t   = hW2t + 3 * 256 * 128;

    // weights + CSR build
    k_trans_all<<<(605568 + 255) / 256, 256, 0, stream>>>(
        gcnW, rW1, rW2, hW1, hW2, hW3, gcnWt, rW1t, rW2t, hW1t, hW2t, hW3t);
    k_zero256<<<1, NBUCK, 0, stream>>>(gcount);
    k_binA<<<NEDGE / 8192, 1024, 0, stream>>>(eidx, tmp, gcount);
    k_scanB<<<1, NBUCK, 0, stream>>>(gcount, bbase, rowptr);
    k_binB<<<NBUCK, 1024, 0, stream>>>(tmp, gcount, bbase, rowptr, dinv, srcs);

    unsigned short* hcur = h0;
    unsigned short* hnxt = h1;
    for (int i = 0; i < NITERS; ++i) {
        unsigned short* hdst = (i == 0) ? h0 : hnxt;
        if (i == 0) {
            k_gcnref<true><<<NN / 64, 256, 0, stream>>>(
                rowptr, srcs, dinv, syn, embW, embB, nullptr,
                gcnWt, gcnB,
                rW1t, rB1, rW2t, rB2, h0);
        } else {
            k_gcnref<false><<<NN / 64, 256, 0, stream>>>(
                rowptr, srcs, dinv, nullptr, nullptr, nullptr, hcur,
                gcnWt + (size_t)i * 64 * 64, gcnB + (size_t)i * 64,
                rW1t + (size_t)i * 64 * 256, rB1 + (size_t)i * 256,
                rW2t + (size_t)i * 256 * 64, rB2 + (size_t)i * 64, hdst);
        }
        k_head<<<NB / 64, 256, 0, stream>>>(
            hdst,
            hW1t + (size_t)i * 512 * 256, hB1 + (size_t)i * 256,
            hW2t + (size_t)i * 256 * 128, hB2 + (size_t)i * 128,
            hW3t + (size_t)i * 128 * 9,   hB3 + (size_t)i * 9,
            out + (size_t)i * NB * NQ);
        if (i == 0) { hcur = h0; hnxt = h1; }
        else { unsigned short* t = hcur; hcur = hdst; hnxt = t; }
    }
}